// Round 7
// baseline (268.503 us; speedup 1.0000x reference)
//
#include <hip/hip_runtime.h>
#include <stdint.h>

typedef __attribute__((ext_vector_type(8))) __bf16 bf16x8;
typedef __attribute__((ext_vector_type(4))) float f32x4;
typedef __attribute__((ext_vector_type(4))) float fl4;
typedef __attribute__((ext_vector_type(8))) unsigned short us8;
typedef __attribute__((ext_vector_type(4))) unsigned short us4;

__device__ __forceinline__ unsigned short f2bf(float f) {
  union { float f; unsigned int u; } v;
  v.f = f;
  unsigned int r = v.u + 0x7FFFu + ((v.u >> 16) & 1u);
  return (unsigned short)(r >> 16);
}

#define GLOAD_LDS16(g, l)                                                   \
  __builtin_amdgcn_global_load_lds(                                         \
      (const __attribute__((address_space(1))) void*)(g),                   \
      (__attribute__((address_space(3))) void*)(l), 16, 0, 0)

// ------------- fused fp32 -> bf16 conversion (x, qkv_w, proj_w) -----------
__global__ void convert_all_kernel(const float* __restrict__ x,
                                   const float* __restrict__ wq,
                                   const float* __restrict__ wp,
                                   unsigned short* __restrict__ ox,
                                   unsigned short* __restrict__ owq,
                                   unsigned short* __restrict__ owp) {
  const int i = (blockIdx.x * blockDim.x + threadIdx.x) * 4;
  const float* src;
  unsigned short* dst;
  int off;
  if (i < 16777216) {
    src = x; dst = ox; off = i;
  } else if (i < 17563648) {
    src = wq; dst = owq; off = i - 16777216;
  } else {
    src = wp; dst = owp; off = i - 17563648;
  }
  fl4 v = *(const fl4*)(src + off);
  us4 o;
  o[0] = f2bf(v[0]);
  o[1] = f2bf(v[1]);
  o[2] = f2bf(v[2]);
  o[3] = f2bf(v[3]);
  *(us4*)(dst + off) = o;
}

// ------- 128x256 8-wave ring-3 counted-vmcnt bf16 NT GEMM ----
// C = A(MxK) * B(NxK)^T + bias. A,B row-major K-contiguous bf16.
// BM=128, BN=256, BK=64, 512 threads (8 waves: 2M x 4N), per-wave C = 64x64
// (4x4 frags) -> 32 FLOP per LDS-byte (vs 21.8 at 64x32): MfmaUtil ceiling
// rises ~40% -> ~60%.  LDS 144 KB: ring of 3 buffers (A 16KB + B 32KB each),
// depth-2 prefetch, counted s_waitcnt vmcnt(6) (never 0 mid-loop) so staging
// latency spans 2 compute tiles; 1 block/CU.
// T2 swizzle byte ^= ((row&7)<<4) via inverse-swizzled global source (linear
// global_load_lds dest) + swizzled ds_read.
// Race discipline (R3 lesson / rule 18): per iter, after MFMAs:
// s_waitcnt lgkmcnt(0) + sched_barrier(0) pins all ds_reads complete before
// the loop-top barrier; stage(kt+2) is issued after that barrier and targets
// buf (kt+2)%3, distinct from this iter's read buf kt%3; the WAR pair
// (reads of kt-1 vs stage of kt+2, same buf) is separated by the barrier.
template <bool OUT_BF16>
__global__ __launch_bounds__(512, 2) void gemm_k3_kernel(
    const unsigned short* __restrict__ A, const unsigned short* __restrict__ B,
    const float* __restrict__ bias, void* __restrict__ Cout, int M, int N,
    int K, int NT) {
  __shared__ __align__(16) unsigned short lds[73728];  // 144 KB
  char* base = (char*)lds;

  const int tid = threadIdx.x;
  const int lane = tid & 63;
  const int wid = tid >> 6;
  const int lr = lane & 15;
  const int lg = lane >> 4;
  const int wm = wid >> 2;  // 0..1 -> 64-row slab (of BM=128)
  const int wn = wid & 3;   // 0..3 -> 64-col slab (of BN=256)

  // supertile-32 mapping: 32 consecutive M-tiles x all NT N-tiles per super-row
  const int bid = blockIdx.x;
  const int bm = ((bid & 31) + (bid / (32 * NT)) * 32) << 7;
  const int bn = ((bid >> 5) % NT) << 8;

  // staging: chunk c covers LDS bytes [c*16, c*16+16): row=c>>3, col16=c&7.
  // A: chunks tid, tid+512 ; B: chunks tid + j*512, j=0..3.
  // source col pre-swizzled so LDS[row][c'] = data[row][c' ^ ((row&7)<<4)]
  // (rows differ by 64 -> same (row&7) -> same swizzle constant per thread).
  const int srow = tid >> 3;  // 0..63
  const int scsw = ((tid & 7) << 4) ^ ((srow & 7) << 4);
  const char* Ag = (const char*)A;
  const char* Bg = (const char*)B;
  const size_t Kb = (size_t)K * 2;

#define STAGE(kt)                                                              \
  {                                                                            \
    char* la_ = base + ((kt) % 3) * 49152;                                     \
    char* lb_ = la_ + 16384;                                                   \
    _Pragma("unroll") for (int i_ = 0; i_ < 2; ++i_) {                         \
      GLOAD_LDS16(Ag + (size_t)(bm + srow + i_ * 64) * Kb + (kt)*128 + scsw,   \
                  la_ + (tid + i_ * 512) * 16);                                \
    }                                                                          \
    _Pragma("unroll") for (int j_ = 0; j_ < 4; ++j_) {                         \
      GLOAD_LDS16(Bg + (size_t)(bn + srow + j_ * 64) * Kb + (kt)*128 + scsw,   \
                  lb_ + (tid + j_ * 512) * 16);                                \
    }                                                                          \
  }

  // swizzled ds_read col offsets
  const int swz = (lr & 7) << 4;
  const int ck0 = (lg << 4) ^ swz;         // kk=0
  const int ck1 = (64 + (lg << 4)) ^ swz;  // kk=1

  f32x4 acc[4][4];
#pragma unroll
  for (int m = 0; m < 4; ++m)
#pragma unroll
    for (int n = 0; n < 4; ++n) acc[m][n] = (f32x4){0.f, 0.f, 0.f, 0.f};

  const int nkt = K >> 6;

  STAGE(0);
  STAGE(1);

  for (int kt = 0; kt < nkt; ++kt) {
    // tile kt landed; kt+1's 6 loads may stay in flight (counted, never 0
    // mid-loop)
    if (kt + 1 < nkt)
      asm volatile("s_waitcnt vmcnt(6)" ::: "memory");
    else
      asm volatile("s_waitcnt vmcnt(0)" ::: "memory");
    __builtin_amdgcn_s_barrier();
    asm volatile("" ::: "memory");
    if (kt + 2 < nkt) STAGE(kt + 2);  // buf (kt+2)%3 != read buf kt%3

    const char* la = base + (kt % 3) * 49152;
    const char* lb = la + 16384;
    bf16x8 af[4][2], bfr[4][2];
#pragma unroll
    for (int m = 0; m < 4; ++m) {
      const int arow = (wm * 64 + m * 16 + lr) << 7;
      af[m][0] = *(const bf16x8*)(la + arow + ck0);
      af[m][1] = *(const bf16x8*)(la + arow + ck1);
    }
#pragma unroll
    for (int n = 0; n < 4; ++n) {
      const int brow = (wn * 64 + n * 16 + lr) << 7;
      bfr[n][0] = *(const bf16x8*)(lb + brow + ck0);
      bfr[n][1] = *(const bf16x8*)(lb + brow + ck1);
    }
#pragma unroll
    for (int kk = 0; kk < 2; ++kk)
#pragma unroll
      for (int m = 0; m < 4; ++m)
#pragma unroll
        for (int n = 0; n < 4; ++n)
          acc[m][n] = __builtin_amdgcn_mfma_f32_16x16x32_bf16(
              af[m][kk], bfr[n][kk], acc[m][n], 0, 0, 0);
    // pin: all ds_reads of buf kt%3 complete before loop-top barrier, and
    // nothing (incl. register-only MFMAs) crosses this point (rule 18)
    asm volatile("s_waitcnt lgkmcnt(0)" ::: "memory");
    __builtin_amdgcn_sched_barrier(0);
  }
#undef STAGE

  // epilogue: C/D layout col = lane&15, row = lg*4 + j
  const int crow0 = bm + wm * 64 + lg * 4;
  const int ccol0 = bn + wn * 64 + lr;
#pragma unroll
  for (int n = 0; n < 4; ++n) {
    const int col = ccol0 + n * 16;
    const float bv = bias[col];
#pragma unroll
    for (int m = 0; m < 4; ++m) {
#pragma unroll
      for (int j = 0; j < 4; ++j) {
        const int row = crow0 + m * 16 + j;
        const float val = acc[m][n][j] + bv;
        if (OUT_BF16)
          ((unsigned short*)Cout)[(size_t)row * N + col] = f2bf(val);
        else
          ((float*)Cout)[(size_t)row * N + col] = val;
      }
    }
  }
}

// ---------------- attention: one WG (4 waves) per (b, h) ----------------
// In-register softmax on S fragments; XCD-chunked block remap.
__global__ __launch_bounds__(256, 4) void attn_kernel(
    const unsigned short* __restrict__ qkv, const float* __restrict__ abias,
    const float* __restrict__ mask, unsigned short* __restrict__ out) {
  __shared__ __align__(16) unsigned short lq[64 * 40];
  __shared__ __align__(16) unsigned short lk[64 * 40];
  __shared__ __align__(16) unsigned short lvT[32 * 72];
  __shared__ __align__(16) unsigned short lp[64 * 72];

  // XCD-chunked: all 16 heads of a window on the same XCD (shared qkv lines)
  const int bid = blockIdx.x;
  const int id2 = (bid & 7) * 1024 + (bid >> 3);
  const int b = id2 >> 4;
  const int h = id2 & 15;
  const int tid = threadIdx.x;
  const int lane = tid & 63;
  const int wid = tid >> 6;
  const int lr = lane & 15;
  const int lg = lane >> 4;
  const int lk8 = lg * 8;

  {
    const int r = tid >> 2;
    const int d0 = (tid & 3) * 8;
    const size_t bse = (size_t)(b * 64 + r) * 1536 + h * 32 + d0;
    us8 qv = *(const us8*)(qkv + bse);
    us8 kv = *(const us8*)(qkv + bse + 512);
    us8 vv = *(const us8*)(qkv + bse + 1024);
    *(us8*)(lq + r * 40 + d0) = qv;
    *(us8*)(lk + r * 40 + d0) = kv;
#pragma unroll
    for (int i = 0; i < 8; ++i) lvT[(d0 + i) * 72 + r] = vv[i];
  }
  __syncthreads();

  // S = q @ k^T (wave owns rows wid*16..+15), fused scale+bias+mask in-frag
  f32x4 s[4];
  {
    bf16x8 aq = *(const bf16x8*)(lq + (wid * 16 + lr) * 40 + lk8);
#pragma unroll
    for (int n = 0; n < 4; ++n) {
      bf16x8 bk = *(const bf16x8*)(lk + (n * 16 + lr) * 40 + lk8);
      f32x4 z = {0.f, 0.f, 0.f, 0.f};
      s[n] = __builtin_amdgcn_mfma_f32_16x16x32_bf16(aq, bk, z, 0, 0, 0);
    }
  }
  const float scale = 0.17677669529663687f;
  const int row0 = wid * 16 + lg * 4;  // + j
#pragma unroll
  for (int j = 0; j < 4; ++j) {
    const int row = row0 + j;
    const float* ab = abias + (h * 64 + row) * 64 + lr;
    const float* mk = mask + ((size_t)b * 64 + row) * 64 + lr;
#pragma unroll
    for (int n = 0; n < 4; ++n)
      s[n][j] = s[n][j] * scale + ab[n * 16] + mk[n * 16];
  }

  // in-register softmax per row j: reduce over n (in-reg) and lr (shfl 16-group)
  float mx[4], sm[4];
#pragma unroll
  for (int j = 0; j < 4; ++j)
    mx[j] = fmaxf(fmaxf(s[0][j], s[1][j]), fmaxf(s[2][j], s[3][j]));
#pragma unroll
  for (int xm = 1; xm <= 8; xm <<= 1)
#pragma unroll
    for (int j = 0; j < 4; ++j) mx[j] = fmaxf(mx[j], __shfl_xor(mx[j], xm));
#pragma unroll
  for (int j = 0; j < 4; ++j) sm[j] = 0.f;
#pragma unroll
  for (int n = 0; n < 4; ++n)
#pragma unroll
    for (int j = 0; j < 4; ++j) {
      const float e = __expf(s[n][j] - mx[j]);
      s[n][j] = e;
      sm[j] += e;
    }
#pragma unroll
  for (int xm = 1; xm <= 8; xm <<= 1)
#pragma unroll
    for (int j = 0; j < 4; ++j) sm[j] += __shfl_xor(sm[j], xm);
#pragma unroll
  for (int j = 0; j < 4; ++j) sm[j] = 1.f / sm[j];
#pragma unroll
  for (int n = 0; n < 4; ++n)
#pragma unroll
    for (int j = 0; j < 4; ++j)
      lp[(row0 + j) * 72 + n * 16 + lr] = f2bf(s[n][j] * sm[j]);
  __syncthreads();

  // O = P @ V
  f32x4 o[2];
  o[0] = (f32x4){0.f, 0.f, 0.f, 0.f};
  o[1] = o[0];
#pragma unroll
  for (int kk = 0; kk < 2; ++kk) {
    bf16x8 pa = *(const bf16x8*)(lp + (wid * 16 + lr) * 72 + kk * 32 + lk8);
#pragma unroll
    for (int d = 0; d < 2; ++d) {
      bf16x8 vb = *(const bf16x8*)(lvT + (d * 16 + lr) * 72 + kk * 32 + lk8);
      o[d] = __builtin_amdgcn_mfma_f32_16x16x32_bf16(pa, vb, o[d], 0, 0, 0);
    }
  }
#pragma unroll
  for (int d = 0; d < 2; ++d) {
    const int col = h * 32 + d * 16 + lr;
#pragma unroll
    for (int j = 0; j < 4; ++j) {
      const int row = row0 + j;
      out[(size_t)(b * 64 + row) * 512 + col] = f2bf(o[d][j]);
    }
  }
}

// ---------------- launch ----------------
extern "C" void kernel_launch(void* const* d_in, const int* in_sizes, int n_in,
                              void* d_out, int out_size, void* d_ws,
                              size_t ws_size, hipStream_t stream) {
  (void)in_sizes; (void)n_in; (void)out_size; (void)ws_size;
  const float* x = (const float*)d_in[0];
  const float* abias = (const float*)d_in[1];
  const float* mask = (const float*)d_in[2];
  const float* qkv_w = (const float*)d_in[3];
  const float* qkv_b = (const float*)d_in[4];
  const float* proj_w = (const float*)d_in[5];
  const float* proj_b = (const float*)d_in[6];

  char* ws = (char*)d_ws;
  unsigned short* ws_x = (unsigned short*)(ws);
  unsigned short* ws_qkv = (unsigned short*)(ws + 33554432);
  unsigned short* ws_wq = (unsigned short*)(ws + 134217728);
  unsigned short* ws_wp = (unsigned short*)(ws + 135790592);
  unsigned short* ws_att = ws_x;  // alias: x consumed by qkv GEMM before attn writes

  // one fused convert dispatch: x (16.7M) + qkv_w (786k) + proj_w (262k)
  convert_all_kernel<<<17408, 256, 0, stream>>>(x, qkv_w, proj_w, ws_x, ws_wq,
                                                ws_wp);

  // qkv: M=32768 (256 M-tiles), N=1536 (NT=6 tiles of 256) -> 1536 blocks
  gemm_k3_kernel<true><<<1536, 512, 0, stream>>>(ws_x, ws_wq, qkv_b, ws_qkv,
                                                 32768, 1536, 512, 6);

  attn_kernel<<<8192, 256, 0, stream>>>(ws_qkv, abias, mask, ws_att);

  // proj: N=512 (NT=2 tiles of 256) -> 512 blocks
  gemm_k3_kernel<false><<<512, 512, 0, stream>>>(ws_att, ws_wp, proj_b, d_out,
                                                 32768, 512, 512, 2);
}

// Round 8
// 265.839 us; speedup vs baseline: 1.0100x; 1.0100x over previous
//
#include <hip/hip_runtime.h>
#include <stdint.h>

typedef __attribute__((ext_vector_type(8))) __bf16 bf16x8;
typedef __attribute__((ext_vector_type(4))) float f32x4;
typedef __attribute__((ext_vector_type(4))) float fl4;
typedef __attribute__((ext_vector_type(8))) unsigned short us8;
typedef __attribute__((ext_vector_type(4))) unsigned short us4;

__device__ __forceinline__ unsigned short f2bf(float f) {
  union { float f; unsigned int u; } v;
  v.f = f;
  unsigned int r = v.u + 0x7FFFu + ((v.u >> 16) & 1u);
  return (unsigned short)(r >> 16);
}

#define GLOAD_LDS16(g, l)                                                   \
  __builtin_amdgcn_global_load_lds(                                         \
      (const __attribute__((address_space(1))) void*)(g),                   \
      (__attribute__((address_space(3))) void*)(l), 16, 0, 0)

// ------------- fused fp32 -> bf16 conversion (x, qkv_w, proj_w) -----------
// grid-stride, 16B/lane f32 loads -> 16B us8 store per iter
__global__ void convert_all_kernel(const float* __restrict__ x,
                                   const float* __restrict__ wq,
                                   const float* __restrict__ wp,
                                   unsigned short* __restrict__ ox,
                                   unsigned short* __restrict__ owq,
                                   unsigned short* __restrict__ owp) {
  const int NCH = 2228224;  // (16777216 + 786432 + 262144) / 8
  const int stride = gridDim.x * blockDim.x;
  for (int c = blockIdx.x * blockDim.x + threadIdx.x; c < NCH; c += stride) {
    const int i = c * 8;
    const float* src;
    unsigned short* dst;
    int off;
    if (i < 16777216) {
      src = x; dst = ox; off = i;
    } else if (i < 17563648) {
      src = wq; dst = owq; off = i - 16777216;
    } else {
      src = wp; dst = owp; off = i - 17563648;
    }
    fl4 v0 = *(const fl4*)(src + off);
    fl4 v1 = *(const fl4*)(src + off + 4);
    us8 o;
    o[0] = f2bf(v0[0]); o[1] = f2bf(v0[1]); o[2] = f2bf(v0[2]); o[3] = f2bf(v0[3]);
    o[4] = f2bf(v1[0]); o[5] = f2bf(v1[1]); o[6] = f2bf(v1[2]); o[7] = f2bf(v1[3]);
    *(us8*)(dst + off) = o;
  }
}

// ------- 128x128 8-wave double-buffered 2-phase bf16 NT GEMM (R6 exact) ----
// C = A(MxK) * B(NxK)^T + bias. BM=BN=128, BK=64, 512 threads (8 waves:
// 2M x 4N), per-wave C = 64x32. LDS 64 KB dbuf, T2 swizzle via pre-swizzled
// global source + swizzled ds_read. One __syncthreads per K-tile (drains
// vmcnt+lgkmcnt -> race-free under graph replay; R3 lesson). 2 blocks/CU x
// 8 waves = 16 waves/CU hides the 2-phase stage+drain stall (R6 proven;
// R2 256^2-8ph and R7 ring-3 both regressed on this thin-K shape).
template <bool OUT_BF16>
__global__ __launch_bounds__(512, 4) void gemm128_kernel(
    const unsigned short* __restrict__ A, const unsigned short* __restrict__ B,
    const float* __restrict__ bias, void* __restrict__ Cout, int M, int N,
    int K, int NT) {
  __shared__ __align__(16) unsigned short lds[32768];  // 64 KB
  char* base = (char*)lds;

  const int tid = threadIdx.x;
  const int lane = tid & 63;
  const int wid = tid >> 6;
  const int lr = lane & 15;
  const int lg = lane >> 4;
  const int wm = wid >> 2;
  const int wn = wid & 3;

  const int bid = blockIdx.x;
  const int bm = ((bid & 31) + (bid / (32 * NT)) * 32) << 7;
  const int bn = (((bid >> 5) % NT)) << 7;

  const int srow = tid >> 3;  // 0..63
  const int scsw = ((tid & 7) << 4) ^ ((srow & 7) << 4);
  const char* Ag = (const char*)A;
  const char* Bg = (const char*)B;
  const size_t Kb = (size_t)K * 2;

#define STAGE(kt, p)                                                           \
  {                                                                            \
    char* la_ = base + (p)*32768;                                              \
    char* lb_ = la_ + 16384;                                                   \
    _Pragma("unroll") for (int i_ = 0; i_ < 2; ++i_) {                         \
      GLOAD_LDS16(Ag + (size_t)(bm + srow + i_ * 64) * Kb + (kt)*128 + scsw,   \
                  la_ + (srow + i_ * 64) * 128 + (tid & 7) * 16);              \
      GLOAD_LDS16(Bg + (size_t)(bn + srow + i_ * 64) * Kb + (kt)*128 + scsw,   \
                  lb_ + (srow + i_ * 64) * 128 + (tid & 7) * 16);              \
    }                                                                          \
  }

  const int swz = (lr & 7) << 4;
  const int ck0 = (lg << 4) ^ swz;
  const int ck1 = (64 + (lg << 4)) ^ swz;

  f32x4 acc[4][2];
#pragma unroll
  for (int m = 0; m < 4; ++m)
#pragma unroll
    for (int n = 0; n < 2; ++n) acc[m][n] = (f32x4){0.f, 0.f, 0.f, 0.f};

  const int nkt = K >> 6;

  STAGE(0, 0);
  __syncthreads();

  for (int kt = 0; kt < nkt; ++kt) {
    const int p = kt & 1;
    if (kt + 1 < nkt) STAGE(kt + 1, p ^ 1);

    const char* la = base + p * 32768;
    const char* lb = la + 16384;
    bf16x8 af[4][2], bfr[2][2];
#pragma unroll
    for (int m = 0; m < 4; ++m) {
      const int arow = (wm * 64 + m * 16 + lr) << 7;
      af[m][0] = *(const bf16x8*)(la + arow + ck0);
      af[m][1] = *(const bf16x8*)(la + arow + ck1);
    }
#pragma unroll
    for (int n = 0; n < 2; ++n) {
      const int brow = (wn * 32 + n * 16 + lr) << 7;
      bfr[n][0] = *(const bf16x8*)(lb + brow + ck0);
      bfr[n][1] = *(const bf16x8*)(lb + brow + ck1);
    }
#pragma unroll
    for (int kk = 0; kk < 2; ++kk)
#pragma unroll
      for (int m = 0; m < 4; ++m)
#pragma unroll
        for (int n = 0; n < 2; ++n)
          acc[m][n] = __builtin_amdgcn_mfma_f32_16x16x32_bf16(
              af[m][kk], bfr[n][kk], acc[m][n], 0, 0, 0);
    __syncthreads();
  }
#undef STAGE

  const int crow0 = bm + wm * 64 + lg * 4;
  const int ccol0 = bn + wn * 32 + lr;
#pragma unroll
  for (int n = 0; n < 2; ++n) {
    const int col = ccol0 + n * 16;
    const float bv = bias[col];
#pragma unroll
    for (int m = 0; m < 4; ++m) {
#pragma unroll
      for (int j = 0; j < 4; ++j) {
        const int row = crow0 + m * 16 + j;
        const float val = acc[m][n][j] + bv;
        if (OUT_BF16)
          ((unsigned short*)Cout)[(size_t)row * N + col] = f2bf(val);
        else
          ((float*)Cout)[(size_t)row * N + col] = val;
      }
    }
  }
}

// ------- attention v2: one WG (4 waves) per (window, head-quad) ----------
// 4 heads processed sequentially; head h+1's q/k/v global loads issued into
// registers BEFORE computing head h (T14: HBM latency hides under compute),
// ds_written to the alternate buffer at round end. Per-head compute = R6's
// verified 4-wave structure (S=QK^T fused scale+bias+mask, in-reg softmax,
// P via LDS, PV). LDS 38 KB -> 4 blocks/CU.
__global__ __launch_bounds__(256, 4) void attn_kernel(
    const unsigned short* __restrict__ qkv, const float* __restrict__ abias,
    const float* __restrict__ mask, unsigned short* __restrict__ out) {
  // per buffer (elems): lq 64*40=2560 | lk 2560 | lvT 32*72=2304  -> 7424
  __shared__ __align__(16) unsigned short bufs[2][7424];
  __shared__ __align__(16) unsigned short lp[64 * 72];

  // XCD-chunked windows: quads of one window land on the same XCD
  const int bid = blockIdx.x;
  const int id2 = (bid & 7) * 256 + (bid >> 3);  // 2048 blocks / 8 XCDs
  const int b = id2 >> 2;
  const int hq = (id2 & 3) << 2;  // first head of this quad
  const int tid = threadIdx.x;
  const int lane = tid & 63;
  const int wid = tid >> 6;
  const int lr = lane & 15;
  const int lg = lane >> 4;
  const int lk8 = lg * 8;
  const int row0 = wid * 16 + lg * 4;
  const float scale = 0.17677669529663687f;  // 32^-0.5

  const int sr = tid >> 2;           // 0..63
  const int sd0 = (tid & 3) * 8;     // 0,8,16,24
  const size_t sbase = (size_t)(b * 64 + sr) * 1536 + sd0;

  us8 qv, kv, vv;
  {
    const unsigned short* p = qkv + sbase + hq * 32;
    qv = *(const us8*)(p);
    kv = *(const us8*)(p + 512);
    vv = *(const us8*)(p + 1024);
  }
  {
    unsigned short* d0b = bufs[0];
    *(us8*)(d0b + sr * 40 + sd0) = qv;
    *(us8*)(d0b + 2560 + sr * 40 + sd0) = kv;
#pragma unroll
    for (int i = 0; i < 8; ++i) d0b[5120 + (sd0 + i) * 72 + sr] = vv[i];
  }
  __syncthreads();

#pragma unroll
  for (int rr = 0; rr < 4; ++rr) {
    const int h = hq + rr;
    if (rr < 3) {  // issue next head's loads early; consumed at round end
      const unsigned short* p = qkv + sbase + (h + 1) * 32;
      qv = *(const us8*)(p);
      kv = *(const us8*)(p + 512);
      vv = *(const us8*)(p + 1024);
    }
    const unsigned short* lq = bufs[rr & 1];
    const unsigned short* lkk = lq + 2560;
    const unsigned short* lvT = lq + 5120;

    // ---- S = q @ k^T, fused scale + bias + mask
    f32x4 s[4];
    {
      bf16x8 aq = *(const bf16x8*)(lq + (wid * 16 + lr) * 40 + lk8);
#pragma unroll
      for (int n = 0; n < 4; ++n) {
        bf16x8 bk = *(const bf16x8*)(lkk + (n * 16 + lr) * 40 + lk8);
        f32x4 z = {0.f, 0.f, 0.f, 0.f};
        s[n] = __builtin_amdgcn_mfma_f32_16x16x32_bf16(aq, bk, z, 0, 0, 0);
      }
    }
#pragma unroll
    for (int j = 0; j < 4; ++j) {
      const int row = row0 + j;
      const float* ab = abias + (h * 64 + row) * 64 + lr;
      const float* mk = mask + ((size_t)b * 64 + row) * 64 + lr;
#pragma unroll
      for (int n = 0; n < 4; ++n)
        s[n][j] = s[n][j] * scale + ab[n * 16] + mk[n * 16];
    }

    // ---- in-register softmax (n in-reg, lr-group via shfl_xor 1/2/4/8)
    float mx[4], sm[4];
#pragma unroll
    for (int j = 0; j < 4; ++j)
      mx[j] = fmaxf(fmaxf(s[0][j], s[1][j]), fmaxf(s[2][j], s[3][j]));
#pragma unroll
    for (int xm = 1; xm <= 8; xm <<= 1)
#pragma unroll
      for (int j = 0; j < 4; ++j) mx[j] = fmaxf(mx[j], __shfl_xor(mx[j], xm));
#pragma unroll
    for (int j = 0; j < 4; ++j) sm[j] = 0.f;
#pragma unroll
    for (int n = 0; n < 4; ++n)
#pragma unroll
      for (int j = 0; j < 4; ++j) {
        const float e = __expf(s[n][j] - mx[j]);
        s[n][j] = e;
        sm[j] += e;
      }
#pragma unroll
    for (int xm = 1; xm <= 8; xm <<= 1)
#pragma unroll
      for (int j = 0; j < 4; ++j) sm[j] += __shfl_xor(sm[j], xm);
#pragma unroll
    for (int j = 0; j < 4; ++j) sm[j] = 1.f / sm[j];
#pragma unroll
    for (int n = 0; n < 4; ++n)
#pragma unroll
      for (int j = 0; j < 4; ++j)
        lp[(row0 + j) * 72 + n * 16 + lr] = f2bf(s[n][j] * sm[j]);
    __syncthreads();

    // ---- O = P @ V
    f32x4 o[2];
    o[0] = (f32x4){0.f, 0.f, 0.f, 0.f};
    o[1] = o[0];
#pragma unroll
    for (int kk = 0; kk < 2; ++kk) {
      bf16x8 pa = *(const bf16x8*)(lp + (wid * 16 + lr) * 72 + kk * 32 + lk8);
#pragma unroll
      for (int d = 0; d < 2; ++d) {
        bf16x8 vb = *(const bf16x8*)(lvT + (d * 16 + lr) * 72 + kk * 32 + lk8);
        o[d] = __builtin_amdgcn_mfma_f32_16x16x32_bf16(pa, vb, o[d], 0, 0, 0);
      }
    }
#pragma unroll
    for (int d = 0; d < 2; ++d) {
      const int col = h * 32 + d * 16 + lr;
#pragma unroll
      for (int j = 0; j < 4; ++j) {
        const int row = row0 + j;
        out[(size_t)(b * 64 + row) * 512 + col] = f2bf(o[d][j]);
      }
    }

    if (rr < 3) {  // write next head's data to the alternate buffer
      unsigned short* db = bufs[(rr + 1) & 1];
      *(us8*)(db + sr * 40 + sd0) = qv;
      *(us8*)(db + 2560 + sr * 40 + sd0) = kv;
#pragma unroll
      for (int i = 0; i < 8; ++i) db[5120 + (sd0 + i) * 72 + sr] = vv[i];
    }
    __syncthreads();  // buffer + lp reuse safe next round
  }
}

// ---------------- launch ----------------
extern "C" void kernel_launch(void* const* d_in, const int* in_sizes, int n_in,
                              void* d_out, int out_size, void* d_ws,
                              size_t ws_size, hipStream_t stream) {
  (void)in_sizes; (void)n_in; (void)out_size; (void)ws_size;
  const float* x = (const float*)d_in[0];
  const float* abias = (const float*)d_in[1];
  const float* mask = (const float*)d_in[2];
  const float* qkv_w = (const float*)d_in[3];
  const float* qkv_b = (const float*)d_in[4];
  const float* proj_w = (const float*)d_in[5];
  const float* proj_b = (const float*)d_in[6];

  char* ws = (char*)d_ws;
  unsigned short* ws_x = (unsigned short*)(ws);
  unsigned short* ws_qkv = (unsigned short*)(ws + 33554432);
  unsigned short* ws_wq = (unsigned short*)(ws + 134217728);
  unsigned short* ws_wp = (unsigned short*)(ws + 135790592);
  unsigned short* ws_att = ws_x;  // alias: x consumed by qkv GEMM before attn writes

  convert_all_kernel<<<2048, 256, 0, stream>>>(x, qkv_w, proj_w, ws_x, ws_wq,
                                               ws_wp);

  // qkv: M=32768 (256 M-tiles), N=1536 (NT=12) -> 3072 blocks
  gemm128_kernel<true><<<3072, 512, 0, stream>>>(ws_x, ws_wq, qkv_b, ws_qkv,
                                                 32768, 1536, 512, 12);

  // attention: 512 windows x 4 head-quads -> 2048 blocks
  attn_kernel<<<2048, 256, 0, stream>>>(ws_qkv, abias, mask, ws_att);

  // proj: N=512 (NT=4) -> 1024 blocks
  gemm128_kernel<false><<<1024, 512, 0, stream>>>(ws_att, ws_wp, proj_b, d_out,
                                                  32768, 512, 512, 4);
}